// Round 1
// baseline (954.854 us; speedup 1.0000x reference)
//
#include <hip/hip_runtime.h>
#include <math.h>

#define NN 10000
#define NE 160000
#define IN_DIM 256
#define HID_DIM 512
#define OUT_DIM 256

// ---------------- degree / normalization ----------------

__global__ void k_init_deg(float* __restrict__ deg) {
    int i = blockIdx.x * blockDim.x + threadIdx.x;
    if (i < NN) deg[i] = 1.0f;  // self loop
}

__global__ void k_count_deg(const int* __restrict__ dst, float* __restrict__ deg) {
    int e = blockIdx.x * blockDim.x + threadIdx.x;
    if (e < NE) atomicAdd(&deg[dst[e]], 1.0f);
}

__global__ void k_rsqrt(float* __restrict__ deg) {
    int i = blockIdx.x * blockDim.x + threadIdx.x;
    if (i < NN) deg[i] = rsqrtf(deg[i]);
}

// ---------------- SGEMM: C[M,N] = A[M,K] @ B[K,N] ----------------
// 64x64 tile, BK=16, 256 threads, 4x4 micro-tile per thread.
// M may be ragged (10000); N,K are multiples of 64/16.

__launch_bounds__(256)
__global__ void k_sgemm(const float* __restrict__ A, const float* __restrict__ B,
                        float* __restrict__ C, int M, int N, int K) {
    __shared__ float As[16][68];  // [k][m], padded (68*4B = 16B-aligned rows)
    __shared__ float Bs[16][68];  // [k][n]

    const int tid = threadIdx.x;
    const int tx = tid & 15;        // n-quad
    const int ty = tid >> 4;        // m-quad
    const int bx = blockIdx.x;      // along N
    const int by = blockIdx.y;      // along M
    const int m_base = by * 64;
    const int n_base = bx * 64;

    const int arow  = tid >> 2;          // 0..63
    const int acol4 = (tid & 3) * 4;     // 0,4,8,12
    const int brow  = tid >> 4;          // 0..15
    const int bcol4 = (tid & 15) * 4;    // 0..60

    float acc[4][4] = {};

    for (int k0 = 0; k0 < K; k0 += 16) {
        // Load A tile (64 rows x 16 cols), store transposed As[k][m]
        float4 av = make_float4(0.f, 0.f, 0.f, 0.f);
        int m = m_base + arow;
        if (m < M) av = *(const float4*)&A[(size_t)m * K + k0 + acol4];
        As[acol4 + 0][arow] = av.x;
        As[acol4 + 1][arow] = av.y;
        As[acol4 + 2][arow] = av.z;
        As[acol4 + 3][arow] = av.w;
        // Load B tile (16 rows x 64 cols)
        float4 bv = *(const float4*)&B[(size_t)(k0 + brow) * N + n_base + bcol4];
        *(float4*)&Bs[brow][bcol4] = bv;
        __syncthreads();

#pragma unroll
        for (int k = 0; k < 16; ++k) {
            float4 a = *(const float4*)&As[k][ty * 4];
            float4 b = *(const float4*)&Bs[k][tx * 4];
            acc[0][0] += a.x * b.x; acc[0][1] += a.x * b.y; acc[0][2] += a.x * b.z; acc[0][3] += a.x * b.w;
            acc[1][0] += a.y * b.x; acc[1][1] += a.y * b.y; acc[1][2] += a.y * b.z; acc[1][3] += a.y * b.w;
            acc[2][0] += a.z * b.x; acc[2][1] += a.z * b.y; acc[2][2] += a.z * b.z; acc[2][3] += a.z * b.w;
            acc[3][0] += a.w * b.x; acc[3][1] += a.w * b.y; acc[3][2] += a.w * b.z; acc[3][3] += a.w * b.w;
        }
        __syncthreads();
    }

#pragma unroll
    for (int i = 0; i < 4; ++i) {
        int m = m_base + ty * 4 + i;
        if (m < M) {
            float4 v = make_float4(acc[i][0], acc[i][1], acc[i][2], acc[i][3]);
            *(float4*)&C[(size_t)m * N + n_base + tx * 4] = v;
        }
    }
}

// ---------------- aggregation ----------------

// agg = h * dinv^2 + bias   (also serves as the zero/poison-clearing init)
__global__ void k_agg_init(const float* __restrict__ h, const float* __restrict__ dinv,
                           const float* __restrict__ bias, float* __restrict__ agg, int F4) {
    int idx = blockIdx.x * blockDim.x + threadIdx.x;
    int total = NN * F4;
    if (idx >= total) return;
    int node = idx / F4;
    int f4 = idx - node * F4;
    float s = dinv[node];
    s *= s;
    float4 hv = ((const float4*)h)[idx];
    float4 bv = ((const float4*)bias)[f4];
    float4 o;
    o.x = hv.x * s + bv.x;
    o.y = hv.y * s + bv.y;
    o.z = hv.z * s + bv.z;
    o.w = hv.w * s + bv.w;
    ((float4*)agg)[idx] = o;
}

// agg[dst] += h[src] * dinv[src]*dinv[dst]  — one block per edge
__global__ void k_scatter(const float* __restrict__ h, const float* __restrict__ dinv,
                          const int* __restrict__ src, const int* __restrict__ dst,
                          float* __restrict__ agg, int F) {
    int e = blockIdx.x;
    int s = src[e], d = dst[e];
    float norm = dinv[s] * dinv[d];
    const float* hp = h + (size_t)s * F;
    float* ap = agg + (size_t)d * F;
    for (int f = threadIdx.x; f < F; f += blockDim.x)
        atomicAdd(&ap[f], hp[f] * norm);
}

__global__ void k_tanh(float* __restrict__ x, int total4) {
    int idx = blockIdx.x * blockDim.x + threadIdx.x;
    if (idx >= total4) return;
    float4 v = ((const float4*)x)[idx];
    v.x = tanhf(v.x); v.y = tanhf(v.y); v.z = tanhf(v.z); v.w = tanhf(v.w);
    ((float4*)x)[idx] = v;
}

// ---------------- launch ----------------

extern "C" void kernel_launch(void* const* d_in, const int* in_sizes, int n_in,
                              void* d_out, int out_size, void* d_ws, size_t ws_size,
                              hipStream_t stream) {
    const float* x  = (const float*)d_in[0];
    const float* W1 = (const float*)d_in[1];
    const float* b1 = (const float*)d_in[2];
    const float* W2 = (const float*)d_in[3];
    const float* b2 = (const float*)d_in[4];
    const float* W3 = (const float*)d_in[5];
    const float* b3 = (const float*)d_in[6];
    const int* edge = (const int*)d_in[7];
    const int* src = edge;
    const int* dst = edge + NE;
    float* out = (float*)d_out;

    // workspace layout
    float* dinv = (float*)d_ws;                                    // 40 KB
    float* bufA = (float*)((char*)d_ws + (1 << 16));               // 20 MB
    float* bufB = (float*)((char*)d_ws + (1 << 16) + (size_t)NN * HID_DIM * 4);  // 20 MB

    const int T = 256;

    // degrees -> dinv
    k_init_deg<<<(NN + T - 1) / T, T, 0, stream>>>(dinv);
    k_count_deg<<<(NE + T - 1) / T, T, 0, stream>>>(dst, dinv);
    k_rsqrt<<<(NN + T - 1) / T, T, 0, stream>>>(dinv);

    // ---- layer 1: x[NN,256] @ W1[256,512] ----
    {
        dim3 grid(HID_DIM / 64, (NN + 63) / 64);
        k_sgemm<<<grid, 256, 0, stream>>>(x, W1, bufA, NN, HID_DIM, IN_DIM);
        int F4 = HID_DIM / 4;
        k_agg_init<<<(NN * F4 + T - 1) / T, T, 0, stream>>>(bufA, dinv, b1, bufB, F4);
        k_scatter<<<NE, T, 0, stream>>>(bufA, dinv, src, dst, bufB, HID_DIM);
        k_tanh<<<(NN * F4 + T - 1) / T, T, 0, stream>>>(bufB, NN * F4);
    }

    // ---- layer 2: bufB[NN,512] @ W2[512,512] ----
    {
        dim3 grid(HID_DIM / 64, (NN + 63) / 64);
        k_sgemm<<<grid, 256, 0, stream>>>(bufB, W2, bufA, NN, HID_DIM, HID_DIM);
        int F4 = HID_DIM / 4;
        k_agg_init<<<(NN * F4 + T - 1) / T, T, 0, stream>>>(bufA, dinv, b2, bufB, F4);
        k_scatter<<<NE, T, 0, stream>>>(bufA, dinv, src, dst, bufB, HID_DIM);
        k_tanh<<<(NN * F4 + T - 1) / T, T, 0, stream>>>(bufB, NN * F4);
    }

    // ---- layer 3: bufB[NN,512] @ W3[512,256] -> d_out ----
    {
        dim3 grid(OUT_DIM / 64, (NN + 63) / 64);
        k_sgemm<<<grid, 256, 0, stream>>>(bufB, W3, bufA, NN, OUT_DIM, HID_DIM);
        int F4 = OUT_DIM / 4;
        k_agg_init<<<(NN * F4 + T - 1) / T, T, 0, stream>>>(bufA, dinv, b3, out, F4);
        k_scatter<<<NE, T, 0, stream>>>(bufA, dinv, src, dst, out, OUT_DIM);
    }
    (void)in_sizes; (void)n_in; (void)out_size; (void)ws_size;
}

// Round 2
// 418.043 us; speedup vs baseline: 2.2841x; 2.2841x over previous
//
#include <hip/hip_runtime.h>
#include <math.h>

#define NN 10000
#define NE 160000
#define IN_DIM 256
#define HID_DIM 512
#define OUT_DIM 256

// ---------------- degree / CSR build ----------------

__global__ void k_zero_deg(int* __restrict__ deg) {
    int i = blockIdx.x * blockDim.x + threadIdx.x;
    if (i < NN) deg[i] = 0;
}

__global__ void k_count_deg(const int* __restrict__ dst, int* __restrict__ deg) {
    int e = blockIdx.x * blockDim.x + threadIdx.x;
    if (e < NE) atomicAdd(&deg[dst[e]], 1);
}

// single block, 256 threads: exclusive prefix sum of deg -> row_start
__global__ void k_scan(const int* __restrict__ deg, int* __restrict__ row_start) {
    __shared__ int sums[256];
    const int tid = threadIdx.x;
    const int CH = 40;  // 256*40 = 10240 >= NN
    int base = tid * CH;
    int s = 0;
    for (int j = 0; j < CH; ++j) {
        int i = base + j;
        if (i < NN) s += deg[i];
    }
    sums[tid] = s;
    __syncthreads();
    for (int off = 1; off < 256; off <<= 1) {
        int t = (tid >= off) ? sums[tid - off] : 0;
        __syncthreads();
        sums[tid] += t;
        __syncthreads();
    }
    int run = sums[tid] - s;  // exclusive prefix for this chunk
    for (int j = 0; j < CH; ++j) {
        int i = base + j;
        if (i < NN) { row_start[i] = run; run += deg[i]; }
    }
}

// dinv = rsqrt(deg + 1)  (self loop)
__global__ void k_deg2dinv(const int* __restrict__ deg, float* __restrict__ dinv) {
    int i = blockIdx.x * blockDim.x + threadIdx.x;
    if (i < NN) dinv[i] = rsqrtf((float)deg[i] + 1.0f);
}

// fill CSR; row[] is row_start on entry, row_end on exit (cursor trick)
__global__ void k_fill(const int* __restrict__ src, const int* __restrict__ dst,
                       int* __restrict__ row, int* __restrict__ csr) {
    int e = blockIdx.x * blockDim.x + threadIdx.x;
    if (e < NE) {
        int pos = atomicAdd(&row[dst[e]], 1);
        csr[pos] = src[e];
    }
}

// ---------------- SGEMM: C[M,N] = A[M,K] @ B[K,N] ----------------
// 128x64 tile, BK=16, 256 threads, 8x4 micro-tile per thread.

__launch_bounds__(256)
__global__ void k_sgemm(const float* __restrict__ A, const float* __restrict__ B,
                        float* __restrict__ C, int M, int N, int K) {
    __shared__ float As[16][132];  // [k][m], 128 + 4 pad
    __shared__ float Bs[16][68];   // [k][n], 64 + 4 pad

    const int tid = threadIdx.x;
    const int m_base = blockIdx.y * 128;
    const int n_base = blockIdx.x * 64;

    const int arow = tid >> 1;          // 0..127
    const int acol = (tid & 1) * 8;     // 0 or 8
    const int brow = tid >> 4;          // 0..15
    const int bcol = (tid & 15) * 4;    // 0..60

    const int ty = tid >> 4;            // 0..15 -> m octet
    const int tx = tid & 15;            // 0..15 -> n quad

    float acc[8][4] = {};

    for (int k0 = 0; k0 < K; k0 += 16) {
        float4 a0 = make_float4(0.f, 0.f, 0.f, 0.f);
        float4 a1 = make_float4(0.f, 0.f, 0.f, 0.f);
        int m = m_base + arow;
        if (m < M) {
            a0 = *(const float4*)&A[(size_t)m * K + k0 + acol];
            a1 = *(const float4*)&A[(size_t)m * K + k0 + acol + 4];
        }
        As[acol + 0][arow] = a0.x; As[acol + 1][arow] = a0.y;
        As[acol + 2][arow] = a0.z; As[acol + 3][arow] = a0.w;
        As[acol + 4][arow] = a1.x; As[acol + 5][arow] = a1.y;
        As[acol + 6][arow] = a1.z; As[acol + 7][arow] = a1.w;
        float4 bv = *(const float4*)&B[(size_t)(k0 + brow) * N + n_base + bcol];
        *(float4*)&Bs[brow][bcol] = bv;
        __syncthreads();

#pragma unroll
        for (int k = 0; k < 16; ++k) {
            float4 va0 = *(const float4*)&As[k][ty * 8];
            float4 va1 = *(const float4*)&As[k][ty * 8 + 4];
            float4 vb  = *(const float4*)&Bs[k][tx * 4];
            float am[8] = {va0.x, va0.y, va0.z, va0.w, va1.x, va1.y, va1.z, va1.w};
            float bn[4] = {vb.x, vb.y, vb.z, vb.w};
#pragma unroll
            for (int i = 0; i < 8; ++i)
#pragma unroll
                for (int j = 0; j < 4; ++j)
                    acc[i][j] += am[i] * bn[j];
        }
        __syncthreads();
    }

#pragma unroll
    for (int i = 0; i < 8; ++i) {
        int m = m_base + ty * 8 + i;
        if (m < M) {
            float4 v = make_float4(acc[i][0], acc[i][1], acc[i][2], acc[i][3]);
            *(float4*)&C[(size_t)m * N + n_base + tx * 4] = v;
        }
    }
}

// ---------------- fused gather aggregation ----------------
// out[d] = act( dinv[d] * ( sum_{s in N(d)} dinv[s]*h[s] + dinv[d]*h[d] ) + b )
// one block per dst node; blockDim = F/4 threads, each owns a float4 lane.

__launch_bounds__(128)
__global__ void k_gather(const float* __restrict__ h, const float* __restrict__ dinv,
                         const int* __restrict__ row_end, const int* __restrict__ csr,
                         const float* __restrict__ bias, float* __restrict__ out,
                         int F4, int do_tanh) {
    const int d = blockIdx.x;
    const int f = threadIdx.x;  // 0..F4-1
    const float dd = dinv[d];
    const int start = (d == 0) ? 0 : row_end[d - 1];
    const int end = row_end[d];

    float4 hv = ((const float4*)h)[(size_t)d * F4 + f];
    float4 acc;
    acc.x = dd * hv.x; acc.y = dd * hv.y; acc.z = dd * hv.z; acc.w = dd * hv.w;

    for (int e = start; e < end; ++e) {
        int s = csr[e];
        float w = dinv[s];
        float4 v = ((const float4*)h)[(size_t)s * F4 + f];
        acc.x += w * v.x; acc.y += w * v.y; acc.z += w * v.z; acc.w += w * v.w;
    }

    float4 bv = ((const float4*)bias)[f];
    acc.x = dd * acc.x + bv.x;
    acc.y = dd * acc.y + bv.y;
    acc.z = dd * acc.z + bv.z;
    acc.w = dd * acc.w + bv.w;
    if (do_tanh) {
        acc.x = tanhf(acc.x); acc.y = tanhf(acc.y);
        acc.z = tanhf(acc.z); acc.w = tanhf(acc.w);
    }
    ((float4*)out)[(size_t)d * F4 + f] = acc;
}

// ---------------- launch ----------------

extern "C" void kernel_launch(void* const* d_in, const int* in_sizes, int n_in,
                              void* d_out, int out_size, void* d_ws, size_t ws_size,
                              hipStream_t stream) {
    const float* x  = (const float*)d_in[0];
    const float* W1 = (const float*)d_in[1];
    const float* b1 = (const float*)d_in[2];
    const float* W2 = (const float*)d_in[3];
    const float* b2 = (const float*)d_in[4];
    const float* W3 = (const float*)d_in[5];
    const float* b3 = (const float*)d_in[6];
    const int* edge = (const int*)d_in[7];
    const int* src = edge;
    const int* dst = edge + NE;
    float* out = (float*)d_out;

    // workspace layout
    char* p = (char*)d_ws;
    float* bufA = (float*)p; p += (size_t)NN * HID_DIM * 4;   // 20.48 MB
    float* bufB = (float*)p; p += (size_t)NN * HID_DIM * 4;   // 20.48 MB
    int*   deg  = (int*)p;   p += (size_t)NN * 4;             // 40 KB
    float* dinv = (float*)p; p += (size_t)NN * 4;             // 40 KB
    int*   row  = (int*)p;   p += (size_t)NN * 4;             // 40 KB (row_start -> row_end)
    int*   csr  = (int*)p;   p += (size_t)NE * 4;             // 640 KB

    const int T = 256;

    // ---- CSR + dinv build ----
    k_zero_deg<<<(NN + T - 1) / T, T, 0, stream>>>(deg);
    k_count_deg<<<(NE + T - 1) / T, T, 0, stream>>>(dst, deg);
    k_scan<<<1, 256, 0, stream>>>(deg, row);
    k_deg2dinv<<<(NN + T - 1) / T, T, 0, stream>>>(deg, dinv);
    k_fill<<<(NE + T - 1) / T, T, 0, stream>>>(src, dst, row, csr);  // row becomes row_end

    const int MB = (NN + 127) / 128;  // 79

    // ---- layer 1: x[NN,256] @ W1 -> bufA; gather -> bufB (tanh) ----
    {
        dim3 grid(HID_DIM / 64, MB);
        k_sgemm<<<grid, 256, 0, stream>>>(x, W1, bufA, NN, HID_DIM, IN_DIM);
        k_gather<<<NN, HID_DIM / 4, 0, stream>>>(bufA, dinv, row, csr, b1, bufB, HID_DIM / 4, 1);
    }

    // ---- layer 2: bufB @ W2 -> bufA; gather -> bufB (tanh) ----
    {
        dim3 grid(HID_DIM / 64, MB);
        k_sgemm<<<grid, 256, 0, stream>>>(bufB, W2, bufA, NN, HID_DIM, HID_DIM);
        k_gather<<<NN, HID_DIM / 4, 0, stream>>>(bufA, dinv, row, csr, b2, bufB, HID_DIM / 4, 1);
    }

    // ---- layer 3: bufB @ W3 -> bufA; gather -> out (no tanh) ----
    {
        dim3 grid(OUT_DIM / 64, MB);
        k_sgemm<<<grid, 256, 0, stream>>>(bufB, W3, bufA, NN, OUT_DIM, HID_DIM);
        k_gather<<<NN, OUT_DIM / 4, 0, stream>>>(bufA, dinv, row, csr, b3, out, OUT_DIM / 4, 0);
    }
    (void)in_sizes; (void)n_in; (void)out_size; (void)ws_size;
}

// Round 3
// 305.793 us; speedup vs baseline: 3.1225x; 1.3671x over previous
//
#include <hip/hip_runtime.h>
#include <math.h>

#define NN 10000
#define NE 160000
#define IN_DIM 256
#define HID_DIM 512
#define OUT_DIM 256

typedef unsigned short u16;
typedef __attribute__((ext_vector_type(8))) short bf16x8;
typedef __attribute__((ext_vector_type(4))) float f32x4;

// ---------------- bf16 split helpers ----------------

static __device__ __forceinline__ u16 f2bf(float f) {
    union { float f; unsigned u; } v; v.f = f;
    unsigned r = v.u + 0x7fffu + ((v.u >> 16) & 1u);  // RNE
    return (u16)(r >> 16);
}
static __device__ __forceinline__ float bf2f(u16 h) {
    union { unsigned u; float f; } v; v.u = ((unsigned)h) << 16;
    return v.f;
}

// ---------------- degree / CSR build ----------------

__global__ void k_zero_deg(int* __restrict__ deg) {
    int i = blockIdx.x * blockDim.x + threadIdx.x;
    if (i < NN) deg[i] = 0;
}

__global__ void k_count_deg(const int* __restrict__ dst, int* __restrict__ deg) {
    int e = blockIdx.x * blockDim.x + threadIdx.x;
    if (e < NE) atomicAdd(&deg[dst[e]], 1);
}

__global__ void k_scan(const int* __restrict__ deg, int* __restrict__ row_start) {
    __shared__ int sums[256];
    const int tid = threadIdx.x;
    const int CH = 40;  // 256*40 >= NN
    int base = tid * CH;
    int s = 0;
    for (int j = 0; j < CH; ++j) {
        int i = base + j;
        if (i < NN) s += deg[i];
    }
    sums[tid] = s;
    __syncthreads();
    for (int off = 1; off < 256; off <<= 1) {
        int t = (tid >= off) ? sums[tid - off] : 0;
        __syncthreads();
        sums[tid] += t;
        __syncthreads();
    }
    int run = sums[tid] - s;
    for (int j = 0; j < CH; ++j) {
        int i = base + j;
        if (i < NN) { row_start[i] = run; run += deg[i]; }
    }
}

__global__ void k_deg2dinv(const int* __restrict__ deg, float* __restrict__ dinv) {
    int i = blockIdx.x * blockDim.x + threadIdx.x;
    if (i < NN) dinv[i] = rsqrtf((float)deg[i] + 1.0f);
}

__global__ void k_fill(const int* __restrict__ src, const int* __restrict__ dst,
                       int* __restrict__ row, int* __restrict__ csr) {
    int e = blockIdx.x * blockDim.x + threadIdx.x;
    if (e < NE) {
        int pos = atomicAdd(&row[dst[e]], 1);
        csr[pos] = src[e];
    }
}

// ---------------- weight transpose + bf16 hi/lo split ----------------
// W[K][N] fp32  ->  T_hi/T_lo[N][K] bf16

__global__ void k_wsplit(const float* __restrict__ W, u16* __restrict__ Thi,
                         u16* __restrict__ Tlo, int K, int N) {
    int idx = blockIdx.x * blockDim.x + threadIdx.x;
    if (idx >= K * N) return;
    int k = idx / N, n = idx - k * N;
    float v = W[idx];
    u16 h = f2bf(v);
    u16 l = f2bf(v - bf2f(h));
    Thi[(size_t)n * K + k] = h;
    Tlo[(size_t)n * K + k] = l;
}

// ---------------- bf16x3 split MFMA GEMM ----------------
// C[M,N] = A[M,K] @ B[K,N] in ~fp32 precision via 3 bf16 MFMA products.
// A given as hi/lo bf16 [M][K]; B given as hi/lo bf16 TRANSPOSED [N][K].
// Tile: BM=128, BN=64, BK=32. 256 threads = 4 waves; wave w owns rows
// [w*32, w*32+32): 2 m-tiles x 4 n-tiles of 16x16.

template<bool HAS_BIAS, bool DO_TANH, bool PAIR_OUT>
__launch_bounds__(256)
__global__ void k_gemm_bf16x3(const u16* __restrict__ Ahi, const u16* __restrict__ Alo,
                              const u16* __restrict__ Bhi, const u16* __restrict__ Blo,
                              const float* __restrict__ bias,
                              float* __restrict__ C, u16* __restrict__ Chi, u16* __restrict__ Clo,
                              int M, int N, int K) {
    __shared__ u16 AsH[128 * 40];  // [m][k], k-row padded 32->40
    __shared__ u16 AsL[128 * 40];
    __shared__ u16 BsH[64 * 40];   // [n][k]
    __shared__ u16 BsL[64 * 40];

    const int tid  = threadIdx.x;
    const int wave = tid >> 6;
    const int lane = tid & 63;
    const int lr   = lane & 15;   // m (A) / n (B) / col (C) within a 16x16 tile
    const int quad = lane >> 4;   // 0..3
    const int m_base = blockIdx.y * 128;
    const int n_base = blockIdx.x * 64;

    f32x4 acc[2][4] = {};

    // staging assignments
    const int a_row0 = tid >> 2;        // chunk c=tid     -> row 0..63
    const int a_q0   = tid & 3;
    const int a_row1 = (tid + 256) >> 2;  // chunk c=tid+256 -> row 64..127
    // a_q1 == a_q0
    const int b_row = tid >> 2;         // 0..63
    const int b_q   = tid & 3;

    for (int k0 = 0; k0 < K; k0 += 32) {
        // ---- stage A (128x32 hi+lo) : 2 chunks/thread/buffer ----
        {
            int rg0 = m_base + a_row0;
            int rg1 = m_base + a_row1;
            uint4 z = make_uint4(0u, 0u, 0u, 0u);
            uint4 h0 = z, l0 = z, h1 = z, l1 = z;
            if (rg0 < M) {
                const u16* p = Ahi + (size_t)rg0 * K + k0 + a_q0 * 8;
                h0 = *(const uint4*)p;
                l0 = *(const uint4*)(Alo + (size_t)rg0 * K + k0 + a_q0 * 8);
            }
            if (rg1 < M) {
                h1 = *(const uint4*)(Ahi + (size_t)rg1 * K + k0 + a_q0 * 8);
                l1 = *(const uint4*)(Alo + (size_t)rg1 * K + k0 + a_q0 * 8);
            }
            *(uint4*)&AsH[a_row0 * 40 + a_q0 * 8] = h0;
            *(uint4*)&AsL[a_row0 * 40 + a_q0 * 8] = l0;
            *(uint4*)&AsH[a_row1 * 40 + a_q0 * 8] = h1;
            *(uint4*)&AsL[a_row1 * 40 + a_q0 * 8] = l1;
        }
        // ---- stage B (64x32 hi+lo) : 1 chunk/thread/buffer ----
        {
            const u16* ph = Bhi + (size_t)(n_base + b_row) * K + k0 + b_q * 8;
            const u16* pl = Blo + (size_t)(n_base + b_row) * K + k0 + b_q * 8;
            *(uint4*)&BsH[b_row * 40 + b_q * 8] = *(const uint4*)ph;
            *(uint4*)&BsL[b_row * 40 + b_q * 8] = *(const uint4*)pl;
        }
        __syncthreads();

        // ---- fragments + MFMA (BK == MFMA K == 32) ----
        bf16x8 aH[2], aL[2], bH[4], bL[4];
#pragma unroll
        for (int tm = 0; tm < 2; ++tm) {
            int m_local = wave * 32 + tm * 16 + lr;
            aH[tm] = *(const bf16x8*)&AsH[m_local * 40 + quad * 8];
            aL[tm] = *(const bf16x8*)&AsL[m_local * 40 + quad * 8];
        }
#pragma unroll
        for (int tn = 0; tn < 4; ++tn) {
            int n_local = tn * 16 + lr;
            bH[tn] = *(const bf16x8*)&BsH[n_local * 40 + quad * 8];
            bL[tn] = *(const bf16x8*)&BsL[n_local * 40 + quad * 8];
        }
#pragma unroll
        for (int tm = 0; tm < 2; ++tm)
#pragma unroll
            for (int tn = 0; tn < 4; ++tn) {
                acc[tm][tn] = __builtin_amdgcn_mfma_f32_16x16x32_bf16(aH[tm], bH[tn], acc[tm][tn], 0, 0, 0);
                acc[tm][tn] = __builtin_amdgcn_mfma_f32_16x16x32_bf16(aH[tm], bL[tn], acc[tm][tn], 0, 0, 0);
                acc[tm][tn] = __builtin_amdgcn_mfma_f32_16x16x32_bf16(aL[tm], bH[tn], acc[tm][tn], 0, 0, 0);
            }
        __syncthreads();
    }

    // ---- epilogue: C/D layout col=lane&15, row=quad*4+i ----
#pragma unroll
    for (int tm = 0; tm < 2; ++tm) {
        int row0 = m_base + wave * 32 + tm * 16 + quad * 4;
#pragma unroll
        for (int tn = 0; tn < 4; ++tn) {
            int col = n_base + tn * 16 + lr;
            float bv = HAS_BIAS ? bias[col] : 0.0f;
#pragma unroll
            for (int i = 0; i < 4; ++i) {
                int row = row0 + i;
                if (row < M) {
                    float v = acc[tm][tn][i] + bv;
                    if (DO_TANH) v = tanhf(v);
                    if (PAIR_OUT) {
                        u16 h = f2bf(v);
                        Chi[(size_t)row * N + col] = h;
                        Clo[(size_t)row * N + col] = f2bf(v - bf2f(h));
                    } else {
                        C[(size_t)row * N + col] = v;
                    }
                }
            }
        }
    }
}

// ---------------- fused gather aggregation ----------------
// res[d] = act( dd * ( sum_{s in N(d)} dinv[s]*h[s]  +  dd*h[d] ) + bias )
// one block per dst node; F4 threads, each owns a float4 lane. 4-edge unroll.

template<bool PAIR_OUT, bool HAS_BIAS, bool DO_TANH>
__global__ void k_gather_t(const float* __restrict__ h, const float* __restrict__ dinv,
                           const int* __restrict__ row_end, const int* __restrict__ csr,
                           const float* __restrict__ bias,
                           float* __restrict__ outF, u16* __restrict__ outH, u16* __restrict__ outL,
                           int F4) {
    const int d = blockIdx.x;
    const int f = threadIdx.x;
    const float dd = dinv[d];
    const int start = (d == 0) ? 0 : row_end[d - 1];
    const int end = row_end[d];
    const float4* h4 = (const float4*)h;

    float4 hv = h4[(size_t)d * F4 + f];
    float ax = dd * hv.x, ay = dd * hv.y, az = dd * hv.z, aw = dd * hv.w;

    int e = start;
    for (; e + 4 <= end; e += 4) {
        int s0 = csr[e], s1 = csr[e + 1], s2 = csr[e + 2], s3 = csr[e + 3];
        float w0 = dinv[s0], w1 = dinv[s1], w2 = dinv[s2], w3 = dinv[s3];
        float4 v0 = h4[(size_t)s0 * F4 + f];
        float4 v1 = h4[(size_t)s1 * F4 + f];
        float4 v2 = h4[(size_t)s2 * F4 + f];
        float4 v3 = h4[(size_t)s3 * F4 + f];
        ax += w0 * v0.x + w1 * v1.x + w2 * v2.x + w3 * v3.x;
        ay += w0 * v0.y + w1 * v1.y + w2 * v2.y + w3 * v3.y;
        az += w0 * v0.z + w1 * v1.z + w2 * v2.z + w3 * v3.z;
        aw += w0 * v0.w + w1 * v1.w + w2 * v2.w + w3 * v3.w;
    }
    for (; e < end; ++e) {
        int s = csr[e];
        float w = dinv[s];
        float4 v = h4[(size_t)s * F4 + f];
        ax += w * v.x; ay += w * v.y; az += w * v.z; aw += w * v.w;
    }

    float rx = dd * ax, ry = dd * ay, rz = dd * az, rw = dd * aw;
    if (HAS_BIAS) {
        float4 bv = ((const float4*)bias)[f];
        rx += bv.x; ry += bv.y; rz += bv.z; rw += bv.w;
    }
    if (DO_TANH) { rx = tanhf(rx); ry = tanhf(ry); rz = tanhf(rz); rw = tanhf(rw); }

    if (PAIR_OUT) {
        u16 hx = f2bf(rx), hy = f2bf(ry), hz = f2bf(rz), hw = f2bf(rw);
        ushort4 vh = make_ushort4(hx, hy, hz, hw);
        ushort4 vl = make_ushort4(f2bf(rx - bf2f(hx)), f2bf(ry - bf2f(hy)),
                                  f2bf(rz - bf2f(hz)), f2bf(rw - bf2f(hw)));
        ((ushort4*)outH)[(size_t)d * F4 + f] = vh;
        ((ushort4*)outL)[(size_t)d * F4 + f] = vl;
    } else {
        ((float4*)outF)[(size_t)d * F4 + f] = make_float4(rx, ry, rz, rw);
    }
}

// ---------------- launch ----------------

extern "C" void kernel_launch(void* const* d_in, const int* in_sizes, int n_in,
                              void* d_out, int out_size, void* d_ws, size_t ws_size,
                              hipStream_t stream) {
    const float* x  = (const float*)d_in[0];
    const float* W1 = (const float*)d_in[1];
    const float* b1 = (const float*)d_in[2];
    const float* W2 = (const float*)d_in[3];
    const float* b2 = (const float*)d_in[4];
    const float* W3 = (const float*)d_in[5];
    const float* b3 = (const float*)d_in[6];
    const int* edge = (const int*)d_in[7];
    const int* src = edge;
    const int* dst = edge + NE;
    float* out = (float*)d_out;

    // ---- workspace layout ----
    const size_t SLOT = (size_t)NN * HID_DIM * 4;  // 20.48 MB
    char* p = (char*)d_ws;
    char* slot0 = p;             // Xagg pair -> H1agg pair -> h3 (f32)
    char* slot1 = p + SLOT;      // h1 (f32)  -> h2 pair
    char* q = p + 2 * SLOT;
    u16* W1Th = (u16*)q; q += (size_t)IN_DIM  * HID_DIM * 2;
    u16* W1Tl = (u16*)q; q += (size_t)IN_DIM  * HID_DIM * 2;
    u16* W2Th = (u16*)q; q += (size_t)HID_DIM * HID_DIM * 2;
    u16* W2Tl = (u16*)q; q += (size_t)HID_DIM * HID_DIM * 2;
    u16* W3Th = (u16*)q; q += (size_t)HID_DIM * OUT_DIM * 2;
    u16* W3Tl = (u16*)q; q += (size_t)HID_DIM * OUT_DIM * 2;
    int*   deg  = (int*)q;   q += (size_t)NN * 4;
    float* dinv = (float*)q; q += (size_t)NN * 4;
    int*   row  = (int*)q;   q += (size_t)NN * 4;
    int*   csr  = (int*)q;   q += (size_t)NE * 4;

    u16* Xagg_h = (u16*)slot0;
    u16* Xagg_l = Xagg_h + (size_t)NN * IN_DIM;
    float* h1   = (float*)slot1;
    u16* H1h    = (u16*)slot0;
    u16* H1l    = H1h + (size_t)NN * HID_DIM;
    u16* h2h    = (u16*)slot1;
    u16* h2l    = h2h + (size_t)NN * HID_DIM;
    float* h3   = (float*)slot0;

    const int T = 256;
    const int MB = (NN + 127) / 128;  // 79

    // ---- CSR + dinv build ----
    k_zero_deg<<<(NN + T - 1) / T, T, 0, stream>>>(deg);
    k_count_deg<<<(NE + T - 1) / T, T, 0, stream>>>(dst, deg);
    k_scan<<<1, 256, 0, stream>>>(deg, row);
    k_deg2dinv<<<(NN + T - 1) / T, T, 0, stream>>>(deg, dinv);
    k_fill<<<(NE + T - 1) / T, T, 0, stream>>>(src, dst, row, csr);

    // ---- weight transpose/split (small) ----
    k_wsplit<<<(IN_DIM * HID_DIM + T - 1) / T, T, 0, stream>>>(W1, W1Th, W1Tl, IN_DIM, HID_DIM);
    k_wsplit<<<(HID_DIM * HID_DIM + T - 1) / T, T, 0, stream>>>(W2, W2Th, W2Tl, HID_DIM, HID_DIM);
    k_wsplit<<<(HID_DIM * OUT_DIM + T - 1) / T, T, 0, stream>>>(W3, W3Th, W3Tl, HID_DIM, OUT_DIM);

    // ---- layer 1: Xagg = S*x (pair out); h1 = tanh(Xagg@W1 + b1) (f32) ----
    k_gather_t<true, false, false><<<NN, IN_DIM / 4, 0, stream>>>(
        x, dinv, row, csr, nullptr, nullptr, Xagg_h, Xagg_l, IN_DIM / 4);
    k_gemm_bf16x3<true, true, false><<<dim3(HID_DIM / 64, MB), 256, 0, stream>>>(
        Xagg_h, Xagg_l, W1Th, W1Tl, b1, h1, nullptr, nullptr, NN, HID_DIM, IN_DIM);

    // ---- layer 2: H1agg = S*h1 (pair out); h2 = tanh(H1agg@W2 + b2) (pair out) ----
    k_gather_t<true, false, false><<<NN, HID_DIM / 4, 0, stream>>>(
        h1, dinv, row, csr, nullptr, nullptr, H1h, H1l, HID_DIM / 4);
    k_gemm_bf16x3<true, true, true><<<dim3(HID_DIM / 64, MB), 256, 0, stream>>>(
        H1h, H1l, W2Th, W2Tl, b2, nullptr, h2h, h2l, NN, HID_DIM, HID_DIM);

    // ---- layer 3: h3 = h2@W3 (f32); out = S*h3 + b3 ----
    k_gemm_bf16x3<false, false, false><<<dim3(OUT_DIM / 64, MB), 256, 0, stream>>>(
        h2h, h2l, W3Th, W3Tl, nullptr, h3, nullptr, nullptr, NN, OUT_DIM, HID_DIM);
    k_gather_t<false, true, false><<<NN, OUT_DIM / 4, 0, stream>>>(
        h3, dinv, row, csr, b3, out, nullptr, nullptr, OUT_DIM / 4);

    (void)in_sizes; (void)n_in; (void)out_size; (void)ws_size;
}

// Round 4
// 299.406 us; speedup vs baseline: 3.1892x; 1.0213x over previous
//
#include <hip/hip_runtime.h>
#include <math.h>

#define NN 10000
#define NE 160000
#define IN_DIM 256
#define HID_DIM 512
#define OUT_DIM 256

typedef unsigned short u16;
typedef __attribute__((ext_vector_type(8))) short bf16x8;
typedef __attribute__((ext_vector_type(4))) float f32x4;

// ---------------- bf16 split helpers ----------------

static __device__ __forceinline__ u16 f2bf(float f) {
    union { float f; unsigned u; } v; v.f = f;
    unsigned r = v.u + 0x7fffu + ((v.u >> 16) & 1u);  // RNE
    return (u16)(r >> 16);
}
static __device__ __forceinline__ float bf2f(u16 h) {
    union { unsigned u; float f; } v; v.u = ((unsigned)h) << 16;
    return v.f;
}

// ---------------- degree / CSR build (self-loops included) ----------------

__global__ void k_zero_deg(int* __restrict__ deg) {
    int i = blockIdx.x * blockDim.x + threadIdx.x;
    if (i < NN) deg[i] = 0;
}

__global__ void k_count_deg(const int* __restrict__ dst, int* __restrict__ deg) {
    int e = blockIdx.x * blockDim.x + threadIdx.x;
    if (e < NE) atomicAdd(&deg[dst[e]], 1);
}

// single block, 1024 threads: LDS-staged scan. Produces:
//   row[i]  = row_start[i] + 1  (cursor past pre-placed self entry)
//   csr[row_start[i]] = i       (self loop at slot 0)
//   dinv[i] = rsqrt(deg+1)
// Row length = deg[i] + 1 (self included).
__launch_bounds__(1024)
__global__ void k_scan(const int* __restrict__ deg, int* __restrict__ row,
                       int* __restrict__ csr, float* __restrict__ dinv) {
    __shared__ int sdeg[10240];
    __shared__ int sums[1024];
    const int tid = threadIdx.x;
    for (int i = tid; i < NN; i += 1024) sdeg[i] = deg[i];
    __syncthreads();
    const int CH = 10;  // 1024*10 >= NN
    int base = tid * CH;
    int s = 0;
    for (int j = 0; j < CH; ++j) {
        int i = base + j;
        if (i < NN) s += sdeg[i] + 1;
    }
    sums[tid] = s;
    __syncthreads();
    for (int off = 1; off < 1024; off <<= 1) {
        int t = (tid >= off) ? sums[tid - off] : 0;
        __syncthreads();
        sums[tid] += t;
        __syncthreads();
    }
    int run = sums[tid] - s;  // exclusive prefix
    for (int j = 0; j < CH; ++j) {
        int i = base + j;
        if (i < NN) {
            int dg = sdeg[i];
            csr[run] = i;        // self entry
            row[i] = run + 1;    // fill cursor starts after self
            dinv[i] = rsqrtf((float)dg + 1.0f);
            run += dg + 1;
        }
    }
}

// fill CSR; row[] is cursor on entry, row_end on exit
__global__ void k_fill(const int* __restrict__ src, const int* __restrict__ dst,
                       int* __restrict__ row, int* __restrict__ csr) {
    int e = blockIdx.x * blockDim.x + threadIdx.x;
    if (e < NE) {
        int pos = atomicAdd(&row[dst[e]], 1);
        csr[pos] = src[e];
    }
}

// ---------------- fused weight transpose + bf16 hi/lo split ----------------
// W[K][N] fp32 -> T_hi/T_lo[N][K] bf16, all three weights in one kernel.

__global__ void k_wsplit_all(const float* __restrict__ W1, const float* __restrict__ W2,
                             const float* __restrict__ W3,
                             u16* __restrict__ W1h, u16* __restrict__ W1l,
                             u16* __restrict__ W2h, u16* __restrict__ W2l,
                             u16* __restrict__ W3h, u16* __restrict__ W3l) {
    int idx = blockIdx.x * blockDim.x + threadIdx.x;
    const int S1 = IN_DIM * HID_DIM;    // 131072
    const int S2 = HID_DIM * HID_DIM;   // 262144
    const int S3 = HID_DIM * OUT_DIM;   // 131072
    const float* W; u16 *Th, *Tl; int K, N, local;
    if (idx < S1)           { W = W1; Th = W1h; Tl = W1l; K = IN_DIM;  N = HID_DIM; local = idx; }
    else if (idx < S1 + S2) { W = W2; Th = W2h; Tl = W2l; K = HID_DIM; N = HID_DIM; local = idx - S1; }
    else if (idx < S1 + S2 + S3) { W = W3; Th = W3h; Tl = W3l; K = HID_DIM; N = OUT_DIM; local = idx - S1 - S2; }
    else return;
    int k = local / N, n = local - k * N;
    float v = W[local];
    u16 h = f2bf(v);
    Th[(size_t)n * K + k] = h;
    Tl[(size_t)n * K + k] = f2bf(v - bf2f(h));
}

// ---------------- bf16x3 split MFMA GEMM ----------------
// C[M,N] = A[M,K] @ B[K,N]; A hi/lo bf16 [M][K]; B hi/lo bf16 transposed [N][K].
// Tile BM=128, BN=64, BK=32; 256 threads = 4 waves; wave owns 32 rows.
// Epilogue: +bias, tanh, *rowscale (dinv prescale for the NEXT gather), per flags.

template<bool HAS_BIAS, bool DO_TANH, bool PAIR_OUT, bool ROWSCALE>
__launch_bounds__(256)
__global__ void k_gemm_bf16x3(const u16* __restrict__ Ahi, const u16* __restrict__ Alo,
                              const u16* __restrict__ Bhi, const u16* __restrict__ Blo,
                              const float* __restrict__ bias, const float* __restrict__ rowscale,
                              float* __restrict__ C, u16* __restrict__ Chi, u16* __restrict__ Clo,
                              int M, int N, int K) {
    __shared__ u16 AsH[128 * 40];
    __shared__ u16 AsL[128 * 40];
    __shared__ u16 BsH[64 * 40];
    __shared__ u16 BsL[64 * 40];

    const int tid  = threadIdx.x;
    const int wave = tid >> 6;
    const int lane = tid & 63;
    const int lr   = lane & 15;
    const int quad = lane >> 4;
    const int m_base = blockIdx.y * 128;
    const int n_base = blockIdx.x * 64;

    f32x4 acc[2][4] = {};

    const int a_row0 = tid >> 2;
    const int a_q0   = tid & 3;
    const int a_row1 = (tid + 256) >> 2;
    const int b_row = tid >> 2;
    const int b_q   = tid & 3;

    for (int k0 = 0; k0 < K; k0 += 32) {
        {
            int rg0 = m_base + a_row0;
            int rg1 = m_base + a_row1;
            uint4 z = make_uint4(0u, 0u, 0u, 0u);
            uint4 h0 = z, l0 = z, h1 = z, l1 = z;
            if (rg0 < M) {
                h0 = *(const uint4*)(Ahi + (size_t)rg0 * K + k0 + a_q0 * 8);
                l0 = *(const uint4*)(Alo + (size_t)rg0 * K + k0 + a_q0 * 8);
            }
            if (rg1 < M) {
                h1 = *(const uint4*)(Ahi + (size_t)rg1 * K + k0 + a_q0 * 8);
                l1 = *(const uint4*)(Alo + (size_t)rg1 * K + k0 + a_q0 * 8);
            }
            *(uint4*)&AsH[a_row0 * 40 + a_q0 * 8] = h0;
            *(uint4*)&AsL[a_row0 * 40 + a_q0 * 8] = l0;
            *(uint4*)&AsH[a_row1 * 40 + a_q0 * 8] = h1;
            *(uint4*)&AsL[a_row1 * 40 + a_q0 * 8] = l1;
        }
        {
            *(uint4*)&BsH[b_row * 40 + b_q * 8] =
                *(const uint4*)(Bhi + (size_t)(n_base + b_row) * K + k0 + b_q * 8);
            *(uint4*)&BsL[b_row * 40 + b_q * 8] =
                *(const uint4*)(Blo + (size_t)(n_base + b_row) * K + k0 + b_q * 8);
        }
        __syncthreads();

        bf16x8 aH[2], aL[2], bH[4], bL[4];
#pragma unroll
        for (int tm = 0; tm < 2; ++tm) {
            int m_local = wave * 32 + tm * 16 + lr;
            aH[tm] = *(const bf16x8*)&AsH[m_local * 40 + quad * 8];
            aL[tm] = *(const bf16x8*)&AsL[m_local * 40 + quad * 8];
        }
#pragma unroll
        for (int tn = 0; tn < 4; ++tn) {
            int n_local = tn * 16 + lr;
            bH[tn] = *(const bf16x8*)&BsH[n_local * 40 + quad * 8];
            bL[tn] = *(const bf16x8*)&BsL[n_local * 40 + quad * 8];
        }
#pragma unroll
        for (int tm = 0; tm < 2; ++tm)
#pragma unroll
            for (int tn = 0; tn < 4; ++tn) {
                acc[tm][tn] = __builtin_amdgcn_mfma_f32_16x16x32_bf16(aH[tm], bH[tn], acc[tm][tn], 0, 0, 0);
                acc[tm][tn] = __builtin_amdgcn_mfma_f32_16x16x32_bf16(aH[tm], bL[tn], acc[tm][tn], 0, 0, 0);
                acc[tm][tn] = __builtin_amdgcn_mfma_f32_16x16x32_bf16(aL[tm], bH[tn], acc[tm][tn], 0, 0, 0);
            }
        __syncthreads();
    }

    // epilogue: C/D layout col=lane&15, row=quad*4+i
#pragma unroll
    for (int tm = 0; tm < 2; ++tm) {
        int row0 = m_base + wave * 32 + tm * 16 + quad * 4;
#pragma unroll
        for (int i = 0; i < 4; ++i) {
            int row = row0 + i;
            if (row >= M) continue;
            float rs = ROWSCALE ? rowscale[row] : 1.0f;
#pragma unroll
            for (int tn = 0; tn < 4; ++tn) {
                int col = n_base + tn * 16 + lr;
                float v = acc[tm][tn][i];
                if (HAS_BIAS) v += bias[col];
                if (DO_TANH) v = tanhf(v);
                if (ROWSCALE) v *= rs;
                if (PAIR_OUT) {
                    u16 h = f2bf(v);
                    Chi[(size_t)row * N + col] = h;
                    Clo[(size_t)row * N + col] = f2bf(v - bf2f(h));
                } else {
                    C[(size_t)row * N + col] = v;
                }
            }
        }
    }
}

// ---------------- fused gather aggregation ----------------
// res[d] = dd * sum_{s in csr(d)} w(s)*h[s]  (+bias)
// self-loop is IN csr. PRESCALED: w==1 (dinv folded into h upstream);
// else w = dinv[s]. 256 threads = NPB nodes per block, 8-edge unroll.

template<bool PRESCALED, bool HAS_BIAS, bool PAIR_OUT, int F4>
__launch_bounds__(256)
__global__ void k_gather(const float* __restrict__ h, const float* __restrict__ dinv,
                         const int* __restrict__ row_end, const int* __restrict__ csr,
                         const float* __restrict__ bias,
                         float* __restrict__ outF, u16* __restrict__ outH, u16* __restrict__ outL) {
    constexpr int NPB = 256 / F4;
    const int tid = threadIdx.x;
    const int d = blockIdx.x * NPB + tid / F4;
    const int f = tid & (F4 - 1);
    if (d >= NN) return;
    const int start = (d == 0) ? 0 : row_end[d - 1];
    const int end = row_end[d];
    const float4* h4 = (const float4*)h;

    float ax = 0.f, ay = 0.f, az = 0.f, aw = 0.f;
    int e = start;
    for (; e + 8 <= end; e += 8) {
        int s[8]; float4 v[8]; float w[8];
#pragma unroll
        for (int j = 0; j < 8; ++j) s[j] = csr[e + j];
#pragma unroll
        for (int j = 0; j < 8; ++j) v[j] = h4[(size_t)s[j] * F4 + f];
#pragma unroll
        for (int j = 0; j < 8; ++j) w[j] = PRESCALED ? 1.0f : dinv[s[j]];
#pragma unroll
        for (int j = 0; j < 8; ++j) {
            ax += w[j] * v[j].x; ay += w[j] * v[j].y;
            az += w[j] * v[j].z; aw += w[j] * v[j].w;
        }
    }
    for (; e < end; ++e) {
        int s = csr[e];
        float w = PRESCALED ? 1.0f : dinv[s];
        float4 v = h4[(size_t)s * F4 + f];
        ax += w * v.x; ay += w * v.y; az += w * v.z; aw += w * v.w;
    }

    const float dd = dinv[d];
    float rx = dd * ax, ry = dd * ay, rz = dd * az, rw = dd * aw;
    if (HAS_BIAS) {
        float4 bv = ((const float4*)bias)[f];
        rx += bv.x; ry += bv.y; rz += bv.z; rw += bv.w;
    }
    if (PAIR_OUT) {
        u16 hx = f2bf(rx), hy = f2bf(ry), hz = f2bf(rz), hw = f2bf(rw);
        ushort4 vh = make_ushort4(hx, hy, hz, hw);
        ushort4 vl = make_ushort4(f2bf(rx - bf2f(hx)), f2bf(ry - bf2f(hy)),
                                  f2bf(rz - bf2f(hz)), f2bf(rw - bf2f(hw)));
        ((ushort4*)outH)[(size_t)d * F4 + f] = vh;
        ((ushort4*)outL)[(size_t)d * F4 + f] = vl;
    } else {
        ((float4*)outF)[(size_t)d * F4 + f] = make_float4(rx, ry, rz, rw);
    }
}

// ---------------- launch ----------------

extern "C" void kernel_launch(void* const* d_in, const int* in_sizes, int n_in,
                              void* d_out, int out_size, void* d_ws, size_t ws_size,
                              hipStream_t stream) {
    const float* x  = (const float*)d_in[0];
    const float* W1 = (const float*)d_in[1];
    const float* b1 = (const float*)d_in[2];
    const float* W2 = (const float*)d_in[3];
    const float* b2 = (const float*)d_in[4];
    const float* W3 = (const float*)d_in[5];
    const float* b3 = (const float*)d_in[6];
    const int* edge = (const int*)d_in[7];
    const int* src = edge;
    const int* dst = edge + NE;
    float* out = (float*)d_out;

    // ---- workspace layout ----
    const size_t SLOT = (size_t)NN * HID_DIM * 4;  // 20.48 MB
    char* p = (char*)d_ws;
    char* slot0 = p;             // Xagg pair -> H1agg pair -> g3 (f32)
    char* slot1 = p + SLOT;      // g1 (f32)  -> h2 pair
    char* q = p + 2 * SLOT;
    u16* W1Th = (u16*)q; q += (size_t)IN_DIM  * HID_DIM * 2;
    u16* W1Tl = (u16*)q; q += (size_t)IN_DIM  * HID_DIM * 2;
    u16* W2Th = (u16*)q; q += (size_t)HID_DIM * HID_DIM * 2;
    u16* W2Tl = (u16*)q; q += (size_t)HID_DIM * HID_DIM * 2;
    u16* W3Th = (u16*)q; q += (size_t)HID_DIM * OUT_DIM * 2;
    u16* W3Tl = (u16*)q; q += (size_t)HID_DIM * OUT_DIM * 2;
    int*   deg  = (int*)q;   q += (size_t)NN * 4;
    float* dinv = (float*)q; q += (size_t)NN * 4;
    int*   row  = (int*)q;   q += (size_t)NN * 4;
    int*   csr  = (int*)q;   q += (size_t)(NE + NN) * 4;

    u16* Xagg_h = (u16*)slot0;
    u16* Xagg_l = Xagg_h + (size_t)NN * IN_DIM;
    float* g1   = (float*)slot1;                    // dinv-prescaled h1
    u16* H1h    = (u16*)slot0;
    u16* H1l    = H1h + (size_t)NN * HID_DIM;
    u16* h2h    = (u16*)slot1;
    u16* h2l    = h2h + (size_t)NN * HID_DIM;
    float* g3   = (float*)slot0;                    // dinv-prescaled h3

    const int T = 256;
    const int MB = (NN + 127) / 128;  // 79

    // ---- CSR (with self loops) + dinv build ----
    k_zero_deg<<<(NN + T - 1) / T, T, 0, stream>>>(deg);
    k_count_deg<<<(NE + T - 1) / T, T, 0, stream>>>(dst, deg);
    k_scan<<<1, 1024, 0, stream>>>(deg, row, csr, dinv);
    k_fill<<<(NE + T - 1) / T, T, 0, stream>>>(src, dst, row, csr);

    // ---- weight transpose/split ----
    {
        int total = IN_DIM * HID_DIM + HID_DIM * HID_DIM + HID_DIM * OUT_DIM;
        k_wsplit_all<<<(total + T - 1) / T, T, 0, stream>>>(W1, W2, W3, W1Th, W1Tl,
                                                            W2Th, W2Tl, W3Th, W3Tl);
    }

    // ---- layer 1: Xagg = S*x (pair); g1 = tanh(Xagg@W1+b1)*dinv (f32) ----
    k_gather<false, false, true, IN_DIM / 4><<<NN / (256 / (IN_DIM / 4)), 256, 0, stream>>>(
        x, dinv, row, csr, nullptr, nullptr, Xagg_h, Xagg_l);
    k_gemm_bf16x3<true, true, false, true><<<dim3(HID_DIM / 64, MB), 256, 0, stream>>>(
        Xagg_h, Xagg_l, W1Th, W1Tl, b1, dinv, g1, nullptr, nullptr, NN, HID_DIM, IN_DIM);

    // ---- layer 2: H1agg = S*g1 (pure sum, pair); h2 = tanh(H1agg@W2+b2) (pair) ----
    k_gather<true, false, true, HID_DIM / 4><<<NN / (256 / (HID_DIM / 4)), 256, 0, stream>>>(
        g1, dinv, row, csr, nullptr, nullptr, H1h, H1l);
    k_gemm_bf16x3<true, true, true, false><<<dim3(HID_DIM / 64, MB), 256, 0, stream>>>(
        H1h, H1l, W2Th, W2Tl, b2, nullptr, nullptr, h2h, h2l, NN, HID_DIM, HID_DIM);

    // ---- layer 3: g3 = (h2@W3)*dinv (f32); out = S*g3 + b3 ----
    k_gemm_bf16x3<false, false, false, true><<<dim3(OUT_DIM / 64, MB), 256, 0, stream>>>(
        h2h, h2l, W3Th, W3Tl, nullptr, dinv, g3, nullptr, nullptr, NN, OUT_DIM, HID_DIM);
    k_gather<true, true, false, OUT_DIM / 4><<<NN / (256 / (OUT_DIM / 4)), 256, 0, stream>>>(
        g3, dinv, row, csr, b3, out, nullptr, nullptr);

    (void)in_sizes; (void)n_in; (void)out_size; (void)ws_size;
}

// Round 5
// 268.950 us; speedup vs baseline: 3.5503x; 1.1132x over previous
//
#include <hip/hip_runtime.h>
#include <math.h>

#define NN 10000
#define NE 160000
#define IN_DIM 256
#define HID_DIM 512
#define OUT_DIM 256

typedef unsigned short u16;
typedef __attribute__((ext_vector_type(8))) short bf16x8;
typedef __attribute__((ext_vector_type(4))) float f32x4;

// ---------------- bf16 split helpers ----------------

static __device__ __forceinline__ u16 f2bf(float f) {
    union { float f; unsigned u; } v; v.f = f;
    unsigned r = v.u + 0x7fffu + ((v.u >> 16) & 1u);  // RNE
    return (u16)(r >> 16);
}
static __device__ __forceinline__ float bf2f(u16 h) {
    union { unsigned u; float f; } v; v.u = ((unsigned)h) << 16;
    return v.f;
}

// ---------------- degree / CSR build (self-loops included) ----------------

__global__ void k_zero_deg(int* __restrict__ deg) {
    int i = blockIdx.x * blockDim.x + threadIdx.x;
    if (i < NN) deg[i] = 0;
}

__global__ void k_count_deg(const int* __restrict__ dst, int* __restrict__ deg) {
    int e = blockIdx.x * blockDim.x + threadIdx.x;
    if (e < NE) atomicAdd(&deg[dst[e]], 1);
}

// single block, 1024 threads: LDS-staged scan. Produces:
//   row[i]  = row_start[i] + 1  (cursor past pre-placed self entry)
//   csr[row_start[i]] = i       (self loop at slot 0)
//   dinv[i] = rsqrt(deg+1)
__launch_bounds__(1024)
__global__ void k_scan(const int* __restrict__ deg, int* __restrict__ row,
                       int* __restrict__ csr, float* __restrict__ dinv) {
    __shared__ int sdeg[10240];
    __shared__ int sums[1024];
    const int tid = threadIdx.x;
    for (int i = tid; i < NN; i += 1024) sdeg[i] = deg[i];
    __syncthreads();
    const int CH = 10;
    int base = tid * CH;
    int s = 0;
    for (int j = 0; j < CH; ++j) {
        int i = base + j;
        if (i < NN) s += sdeg[i] + 1;
    }
    sums[tid] = s;
    __syncthreads();
    for (int off = 1; off < 1024; off <<= 1) {
        int t = (tid >= off) ? sums[tid - off] : 0;
        __syncthreads();
        sums[tid] += t;
        __syncthreads();
    }
    int run = sums[tid] - s;
    for (int j = 0; j < CH; ++j) {
        int i = base + j;
        if (i < NN) {
            int dg = sdeg[i];
            csr[run] = i;
            row[i] = run + 1;
            dinv[i] = rsqrtf((float)dg + 1.0f);
            run += dg + 1;
        }
    }
}

__global__ void k_fill(const int* __restrict__ src, const int* __restrict__ dst,
                       int* __restrict__ row, int* __restrict__ csr) {
    int e = blockIdx.x * blockDim.x + threadIdx.x;
    if (e < NE) {
        int pos = atomicAdd(&row[dst[e]], 1);
        csr[pos] = src[e];
    }
}

// ---------------- fused weight transpose + bf16 hi/lo split ----------------

__global__ void k_wsplit_all(const float* __restrict__ W1, const float* __restrict__ W2,
                             const float* __restrict__ W3,
                             u16* __restrict__ W1h, u16* __restrict__ W1l,
                             u16* __restrict__ W2h, u16* __restrict__ W2l,
                             u16* __restrict__ W3h, u16* __restrict__ W3l) {
    int idx = blockIdx.x * blockDim.x + threadIdx.x;
    const int S1 = IN_DIM * HID_DIM;
    const int S2 = HID_DIM * HID_DIM;
    const int S3 = HID_DIM * OUT_DIM;
    const float* W; u16 *Th, *Tl; int K, N, local;
    if (idx < S1)           { W = W1; Th = W1h; Tl = W1l; K = IN_DIM;  N = HID_DIM; local = idx; }
    else if (idx < S1 + S2) { W = W2; Th = W2h; Tl = W2l; K = HID_DIM; N = HID_DIM; local = idx - S1; }
    else if (idx < S1 + S2 + S3) { W = W3; Th = W3h; Tl = W3l; K = HID_DIM; N = OUT_DIM; local = idx - S1 - S2; }
    else return;
    int k = local / N, n = local - k * N;
    float v = W[local];
    u16 h = f2bf(v);
    Th[(size_t)n * K + k] = h;
    Tl[(size_t)n * K + k] = f2bf(v - bf2f(h));
}

// ---------------- bf16x3 split MFMA GEMM ----------------

template<bool HAS_BIAS, bool DO_TANH, bool PAIR_OUT, bool ROWSCALE>
__launch_bounds__(256)
__global__ void k_gemm_bf16x3(const u16* __restrict__ Ahi, const u16* __restrict__ Alo,
                              const u16* __restrict__ Bhi, const u16* __restrict__ Blo,
                              const float* __restrict__ bias, const float* __restrict__ rowscale,
                              float* __restrict__ C, u16* __restrict__ Chi, u16* __restrict__ Clo,
                              int M, int N, int K) {
    __shared__ u16 AsH[128 * 40];
    __shared__ u16 AsL[128 * 40];
    __shared__ u16 BsH[64 * 40];
    __shared__ u16 BsL[64 * 40];

    const int tid  = threadIdx.x;
    const int wave = tid >> 6;
    const int lane = tid & 63;
    const int lr   = lane & 15;
    const int quad = lane >> 4;
    const int m_base = blockIdx.y * 128;
    const int n_base = blockIdx.x * 64;

    f32x4 acc[2][4] = {};

    const int a_row0 = tid >> 2;
    const int a_q0   = tid & 3;
    const int a_row1 = (tid + 256) >> 2;
    const int b_row = tid >> 2;
    const int b_q   = tid & 3;

    for (int k0 = 0; k0 < K; k0 += 32) {
        {
            int rg0 = m_base + a_row0;
            int rg1 = m_base + a_row1;
            uint4 z = make_uint4(0u, 0u, 0u, 0u);
            uint4 h0 = z, l0 = z, h1 = z, l1 = z;
            if (rg0 < M) {
                h0 = *(const uint4*)(Ahi + (size_t)rg0 * K + k0 + a_q0 * 8);
                l0 = *(const uint4*)(Alo + (size_t)rg0 * K + k0 + a_q0 * 8);
            }
            if (rg1 < M) {
                h1 = *(const uint4*)(Ahi + (size_t)rg1 * K + k0 + a_q0 * 8);
                l1 = *(const uint4*)(Alo + (size_t)rg1 * K + k0 + a_q0 * 8);
            }
            *(uint4*)&AsH[a_row0 * 40 + a_q0 * 8] = h0;
            *(uint4*)&AsL[a_row0 * 40 + a_q0 * 8] = l0;
            *(uint4*)&AsH[a_row1 * 40 + a_q0 * 8] = h1;
            *(uint4*)&AsL[a_row1 * 40 + a_q0 * 8] = l1;
        }
        {
            *(uint4*)&BsH[b_row * 40 + b_q * 8] =
                *(const uint4*)(Bhi + (size_t)(n_base + b_row) * K + k0 + b_q * 8);
            *(uint4*)&BsL[b_row * 40 + b_q * 8] =
                *(const uint4*)(Blo + (size_t)(n_base + b_row) * K + k0 + b_q * 8);
        }
        __syncthreads();

        bf16x8 aH[2], aL[2], bH[4], bL[4];
#pragma unroll
        for (int tm = 0; tm < 2; ++tm) {
            int m_local = wave * 32 + tm * 16 + lr;
            aH[tm] = *(const bf16x8*)&AsH[m_local * 40 + quad * 8];
            aL[tm] = *(const bf16x8*)&AsL[m_local * 40 + quad * 8];
        }
#pragma unroll
        for (int tn = 0; tn < 4; ++tn) {
            int n_local = tn * 16 + lr;
            bH[tn] = *(const bf16x8*)&BsH[n_local * 40 + quad * 8];
            bL[tn] = *(const bf16x8*)&BsL[n_local * 40 + quad * 8];
        }
#pragma unroll
        for (int tm = 0; tm < 2; ++tm)
#pragma unroll
            for (int tn = 0; tn < 4; ++tn) {
                acc[tm][tn] = __builtin_amdgcn_mfma_f32_16x16x32_bf16(aH[tm], bH[tn], acc[tm][tn], 0, 0, 0);
                acc[tm][tn] = __builtin_amdgcn_mfma_f32_16x16x32_bf16(aH[tm], bL[tn], acc[tm][tn], 0, 0, 0);
                acc[tm][tn] = __builtin_amdgcn_mfma_f32_16x16x32_bf16(aL[tm], bH[tn], acc[tm][tn], 0, 0, 0);
            }
        __syncthreads();
    }

#pragma unroll
    for (int tm = 0; tm < 2; ++tm) {
        int row0 = m_base + wave * 32 + tm * 16 + quad * 4;
#pragma unroll
        for (int i = 0; i < 4; ++i) {
            int row = row0 + i;
            if (row >= M) continue;
            float rs = ROWSCALE ? rowscale[row] : 1.0f;
#pragma unroll
            for (int tn = 0; tn < 4; ++tn) {
                int col = n_base + tn * 16 + lr;
                float v = acc[tm][tn][i];
                if (HAS_BIAS) v += bias[col];
                if (DO_TANH) v = tanhf(v);
                if (ROWSCALE) v *= rs;
                if (PAIR_OUT) {
                    u16 h = f2bf(v);
                    Chi[(size_t)row * N + col] = h;
                    Clo[(size_t)row * N + col] = f2bf(v - bf2f(h));
                } else {
                    C[(size_t)row * N + col] = v;
                }
            }
        }
    }
}

// ---------------- XCD-sliced fused gather aggregation ----------------
// res[d] = dd * sum_{s in csr(d)} w(s)*h[s]  (+bias); self-loop IS in csr.
// Feature dim split into 8 slices; block b -> slice b%8 (one slice per XCD
// via the round-robin blockIdx->XCD mapping), node group b/8. Each XCD's L2
// then only ever caches 1/8 of the h table -> ~5x less L2-fill traffic.

template<bool PRESCALED, bool HAS_BIAS, bool PAIR_OUT, int F4>
__launch_bounds__(256)
__global__ void k_gather(const float* __restrict__ h, const float* __restrict__ dinv,
                         const int* __restrict__ row_end, const int* __restrict__ csr,
                         const float* __restrict__ bias,
                         float* __restrict__ outF, u16* __restrict__ outH, u16* __restrict__ outL) {
    constexpr int NS = 8;
    constexpr int F4S = F4 / NS;       // float4 lanes per node per slice
    constexpr int NPB = 256 / F4S;     // nodes per block
    const int slice = blockIdx.x & (NS - 1);
    const int g = blockIdx.x >> 3;
    const int tid = threadIdx.x;
    const int d = g * NPB + tid / F4S;
    if (d >= NN) return;
    const int f = slice * F4S + (tid & (F4S - 1));

    const int start = (d == 0) ? 0 : row_end[d - 1];
    const int end = row_end[d];
    const float4* h4 = (const float4*)h;

    float ax = 0.f, ay = 0.f, az = 0.f, aw = 0.f;
    int e = start;
    for (; e + 8 <= end; e += 8) {
        int s[8]; float4 v[8]; float w[8];
#pragma unroll
        for (int j = 0; j < 8; ++j) s[j] = csr[e + j];
#pragma unroll
        for (int j = 0; j < 8; ++j) v[j] = h4[(size_t)s[j] * F4 + f];
#pragma unroll
        for (int j = 0; j < 8; ++j) w[j] = PRESCALED ? 1.0f : dinv[s[j]];
#pragma unroll
        for (int j = 0; j < 8; ++j) {
            ax += w[j] * v[j].x; ay += w[j] * v[j].y;
            az += w[j] * v[j].z; aw += w[j] * v[j].w;
        }
    }
    for (; e < end; ++e) {
        int s = csr[e];
        float w = PRESCALED ? 1.0f : dinv[s];
        float4 v = h4[(size_t)s * F4 + f];
        ax += w * v.x; ay += w * v.y; az += w * v.z; aw += w * v.w;
    }

    const float dd = dinv[d];
    float rx = dd * ax, ry = dd * ay, rz = dd * az, rw = dd * aw;
    if (HAS_BIAS) {
        float4 bv = ((const float4*)bias)[f];
        rx += bv.x; ry += bv.y; rz += bv.z; rw += bv.w;
    }
    if (PAIR_OUT) {
        u16 hx = f2bf(rx), hy = f2bf(ry), hz = f2bf(rz), hw = f2bf(rw);
        ushort4 vh = make_ushort4(hx, hy, hz, hw);
        ushort4 vl = make_ushort4(f2bf(rx - bf2f(hx)), f2bf(ry - bf2f(hy)),
                                  f2bf(rz - bf2f(hz)), f2bf(rw - bf2f(hw)));
        ((ushort4*)outH)[(size_t)d * F4 + f] = vh;
        ((ushort4*)outL)[(size_t)d * F4 + f] = vl;
    } else {
        ((float4*)outF)[(size_t)d * F4 + f] = make_float4(rx, ry, rz, rw);
    }
}

// ---------------- launch ----------------

extern "C" void kernel_launch(void* const* d_in, const int* in_sizes, int n_in,
                              void* d_out, int out_size, void* d_ws, size_t ws_size,
                              hipStream_t stream) {
    const float* x  = (const float*)d_in[0];
    const float* W1 = (const float*)d_in[1];
    const float* b1 = (const float*)d_in[2];
    const float* W2 = (const float*)d_in[3];
    const float* b2 = (const float*)d_in[4];
    const float* W3 = (const float*)d_in[5];
    const float* b3 = (const float*)d_in[6];
    const int* edge = (const int*)d_in[7];
    const int* src = edge;
    const int* dst = edge + NE;
    float* out = (float*)d_out;

    const size_t SLOT = (size_t)NN * HID_DIM * 4;
    char* p = (char*)d_ws;
    char* slot0 = p;
    char* slot1 = p + SLOT;
    char* q = p + 2 * SLOT;
    u16* W1Th = (u16*)q; q += (size_t)IN_DIM  * HID_DIM * 2;
    u16* W1Tl = (u16*)q; q += (size_t)IN_DIM  * HID_DIM * 2;
    u16* W2Th = (u16*)q; q += (size_t)HID_DIM * HID_DIM * 2;
    u16* W2Tl = (u16*)q; q += (size_t)HID_DIM * HID_DIM * 2;
    u16* W3Th = (u16*)q; q += (size_t)HID_DIM * OUT_DIM * 2;
    u16* W3Tl = (u16*)q; q += (size_t)HID_DIM * OUT_DIM * 2;
    int*   deg  = (int*)q;   q += (size_t)NN * 4;
    float* dinv = (float*)q; q += (size_t)NN * 4;
    int*   row  = (int*)q;   q += (size_t)NN * 4;
    int*   csr  = (int*)q;   q += (size_t)(NE + NN) * 4;

    u16* Xagg_h = (u16*)slot0;
    u16* Xagg_l = Xagg_h + (size_t)NN * IN_DIM;
    float* g1   = (float*)slot1;
    u16* H1h    = (u16*)slot0;
    u16* H1l    = H1h + (size_t)NN * HID_DIM;
    u16* h2h    = (u16*)slot1;
    u16* h2l    = h2h + (size_t)NN * HID_DIM;
    float* g3   = (float*)slot0;

    const int T = 256;
    const int MB = (NN + 127) / 128;

    // ---- CSR (with self loops) + dinv build ----
    k_zero_deg<<<(NN + T - 1) / T, T, 0, stream>>>(deg);
    k_count_deg<<<(NE + T - 1) / T, T, 0, stream>>>(dst, deg);
    k_scan<<<1, 1024, 0, stream>>>(deg, row, csr, dinv);
    k_fill<<<(NE + T - 1) / T, T, 0, stream>>>(src, dst, row, csr);

    {
        int total = IN_DIM * HID_DIM + HID_DIM * HID_DIM + HID_DIM * OUT_DIM;
        k_wsplit_all<<<(total + T - 1) / T, T, 0, stream>>>(W1, W2, W3, W1Th, W1Tl,
                                                            W2Th, W2Tl, W3Th, W3Tl);
    }

    // gather grids: 8 slices x node groups
    const int G256 = ((NN + 31) / 32) * 8;   // F4=64 -> NPB=32
    const int G512 = ((NN + 15) / 16) * 8;   // F4=128 -> NPB=16

    // ---- layer 1: Xagg = S*x (pair); g1 = tanh(Xagg@W1+b1)*dinv (f32) ----
    k_gather<false, false, true, IN_DIM / 4><<<G256, 256, 0, stream>>>(
        x, dinv, row, csr, nullptr, nullptr, Xagg_h, Xagg_l);
    k_gemm_bf16x3<true, true, false, true><<<dim3(HID_DIM / 64, MB), 256, 0, stream>>>(
        Xagg_h, Xagg_l, W1Th, W1Tl, b1, dinv, g1, nullptr, nullptr, NN, HID_DIM, IN_DIM);

    // ---- layer 2: H1agg = S*g1 (pure sum, pair); h2 = tanh(H1agg@W2+b2) (pair) ----
    k_gather<true, false, true, HID_DIM / 4><<<G512, 256, 0, stream>>>(
        g1, dinv, row, csr, nullptr, nullptr, H1h, H1l);
    k_gemm_bf16x3<true, true, true, false><<<dim3(HID_DIM / 64, MB), 256, 0, stream>>>(
        H1h, H1l, W2Th, W2Tl, b2, nullptr, nullptr, h2h, h2l, NN, HID_DIM, HID_DIM);

    // ---- layer 3: g3 = (h2@W3)*dinv (f32); out = S*g3 + b3 ----
    k_gemm_bf16x3<false, false, false, true><<<dim3(OUT_DIM / 64, MB), 256, 0, stream>>>(
        h2h, h2l, W3Th, W3Tl, nullptr, dinv, g3, nullptr, nullptr, NN, OUT_DIM, HID_DIM);
    k_gather<true, true, false, OUT_DIM / 4><<<G256, 256, 0, stream>>>(
        g3, dinv, row, csr, b3, out, nullptr, nullptr);

    (void)in_sizes; (void)n_in; (void)out_size; (void)ws_size;
}